// Round 2
// baseline (5095.134 us; speedup 1.0000x reference)
//
#include <hip/hip_runtime.h>
#include <hip/hip_bf16.h>

#define BB 1024
#define NN 81
#define EE 1620
#define HH 128
#define MM 128
#define G3 384
#define NSTEPS 8
#define RR (BB*NN)   // 82944 rows

// ---------------------------------------------------------------------------
// prep_graph: bucket edges by receiver (CSR), deterministic, single block.
// NOTE: harness passes integer inputs as int32.
// ---------------------------------------------------------------------------
__global__ __launch_bounds__(128) void prep_graph(const int* __restrict__ ei,
                                                  int* __restrict__ goff,
                                                  int* __restrict__ gcnt,
                                                  int* __restrict__ gsend) {
    __shared__ int eis[2 * EE];
    __shared__ int cs[NN];
    __shared__ int offs[NN + 1];
    int tid = threadIdx.x;
    for (int i = tid; i < 2 * EE; i += 128) eis[i] = ei[i];
    __syncthreads();
    if (tid < NN) {
        int c = 0;
        for (int e = 0; e < EE; e++) if (eis[EE + e] == tid) c++;
        cs[tid] = c;
    }
    __syncthreads();
    if (tid == 0) {
        int o = 0;
        for (int r = 0; r < NN; r++) { offs[r] = o; o += cs[r]; }
        offs[NN] = o;
    }
    __syncthreads();
    if (tid < NN) {
        int pos = offs[tid];
        for (int e = 0; e < EE; e++) {
            if (eis[EE + e] == tid) gsend[pos++] = eis[e];
        }
        goff[tid] = offs[tid];
        gcnt[tid] = cs[tid];
    }
    if (tid == 0) goff[NN] = offs[NN];
}

// ---------------------------------------------------------------------------
// prep_wc: Wc = W_ih @ W_m2  (384x128), stored transposed-quad for k3;
//          biasWc = W_ih @ b_m2 (384)
// layout: WtA4[((k>>2)*384 + o)*4 + (k&3)] = Wc[o][k]
// ---------------------------------------------------------------------------
__global__ __launch_bounds__(256) void prep_wc(const float* __restrict__ W_ih,
                                               const float* __restrict__ W_m2,
                                               const float* __restrict__ b_m2,
                                               float* __restrict__ WtA4,
                                               float* __restrict__ biasWc) {
    int idx = blockIdx.x * 256 + threadIdx.x;
    if (idx >= G3 * HH) return;
    int o = idx >> 7;          // /128
    int k = idx & 127;
    float acc = 0.f;
    for (int m = 0; m < MM; m++) acc += W_ih[o * MM + m] * W_m2[m * MM + k];
    WtA4[((k >> 2) * G3 + o) * 4 + (k & 3)] = acc;
    if (k == 0) {
        float bb = 0.f;
        for (int m = 0; m < MM; m++) bb += W_ih[o * MM + m] * b_m2[m];
        biasWc[o] = bb;
    }
}

// ---------------------------------------------------------------------------
// prep_trans: transpose weight matrices into [k4][col][4] quad layout
// ---------------------------------------------------------------------------
__global__ __launch_bounds__(256) void prep_trans(const float* __restrict__ W_m1,
                                                  const float* __restrict__ W_hh,
                                                  const float* __restrict__ W_o1,
                                                  float* __restrict__ WtK1,
                                                  float* __restrict__ WtB4,
                                                  float* __restrict__ WtO1) {
    int idx = blockIdx.x * 256 + threadIdx.x;
    if (idx < 128 * 256) {
        int k = idx >> 8;
        int j = idx & 255;
        float v = (j < 128) ? W_m1[j * 256 + k] : W_m1[(j - 128) * 256 + 128 + k];
        WtK1[((k >> 2) * 256 + j) * 4 + (k & 3)] = v;
    }
    if (idx < 128 * G3) {
        int k = idx / G3;
        int o = idx - k * G3;
        WtB4[((k >> 2) * G3 + o) * 4 + (k & 3)] = W_hh[o * HH + k];
    }
    if (idx < 128 * 128) {
        int k = idx >> 7;
        int j = idx & 127;
        WtO1[((k >> 2) * 128 + j) * 4 + (k & 3)] = W_o1[j * HH + k];
    }
}

// ---------------------------------------------------------------------------
// input_proj: h = x @ W_in.T + b_in    (R x 10) -> (R x 128)
// ---------------------------------------------------------------------------
__global__ __launch_bounds__(256) void input_proj(const float* __restrict__ x,
                                                  const float* __restrict__ W_in,
                                                  const float* __restrict__ b_in,
                                                  float* __restrict__ h) {
    long idx = (long)blockIdx.x * 256 + threadIdx.x;   // R*H total
    long row = idx >> 7;
    int o = (int)(idx & 127);
    const float* xr = x + row * 10;
    const float* w = W_in + o * 10;
    float acc = b_in[o];
#pragma unroll
    for (int k = 0; k < 10; k++) acc += xr[k] * w[k];
    h[idx] = acc;
}

// ---------------------------------------------------------------------------
// k1_gemm: hAB = h @ [W_m1a | W_m1b].T (+ b_m1 on recv half)
// ---------------------------------------------------------------------------
#define TM1 16
__global__ __launch_bounds__(256) void k1_gemm(const float* __restrict__ h,
                                               const float* __restrict__ WtK1,
                                               const float* __restrict__ b_m1,
                                               float* __restrict__ hAB) {
    __shared__ float hs[TM1 * 128];
    int tid = threadIdx.x;
    long rowBase = (long)blockIdx.x * TM1;
    const float4* src = (const float4*)(h + rowBase * 128);
    ((float4*)hs)[tid] = src[tid];
    ((float4*)hs)[tid + 256] = src[tid + 256];
    __syncthreads();
    float acc[TM1];
#pragma unroll
    for (int r = 0; r < TM1; r++) acc[r] = 0.f;
    const float4* W = (const float4*)WtK1;
#pragma unroll 2
    for (int k4 = 0; k4 < 32; k4++) {
        float4 w = W[k4 * 256 + tid];
#pragma unroll
        for (int r = 0; r < TM1; r++) {
            float4 hv = *((const float4*)&hs[r * 128 + k4 * 4]);
            acc[r] = fmaf(hv.x, w.x, acc[r]);
            acc[r] = fmaf(hv.y, w.y, acc[r]);
            acc[r] = fmaf(hv.z, w.z, acc[r]);
            acc[r] = fmaf(hv.w, w.w, acc[r]);
        }
    }
    float bias = (tid >= 128) ? b_m1[tid - 128] : 0.f;
#pragma unroll
    for (int r = 0; r < TM1; r++) {
        hAB[(rowBase + r) * 256 + tid] = acc[r] + bias;
    }
}

// ---------------------------------------------------------------------------
// k2_edges: sum[b,r,:] = sum over incoming edges e (s->r) of
//           relu( hA[b,s,:] + hB'[b,r,:] )
// ---------------------------------------------------------------------------
__global__ __launch_bounds__(128) void k2_edges(const float* __restrict__ hAB,
                                                const int* __restrict__ goff,
                                                const int* __restrict__ gsend,
                                                float* __restrict__ sm) {
    int row = blockIdx.x;              // b*NN + r
    int b = row / NN;
    int r = row - b * NN;
    int m = threadIdx.x;
    float hb = hAB[(long)row * 256 + 128 + m];
    int e0 = goff[r], e1 = goff[r + 1];
    float acc = 0.f;
    long base = (long)b * NN;
    for (int e = e0; e < e1; e++) {
        int s = gsend[e];
        float a = hAB[(base + s) * 256 + m];
        float p = a + hb;
        acc += (p > 0.f) ? p : 0.f;
    }
    sm[(long)row * 128 + m] = acc;
}

// ---------------------------------------------------------------------------
// k3_gru: gi = sm @ Wc.T + cnt*biasWc + b_ih ; gh = h @ W_hh.T + b_hh
//         GRU gates -> h (in place).
// ---------------------------------------------------------------------------
#define TM3 8
__global__ __launch_bounds__(384) void k3_gru(float* __restrict__ h,
                                              const float* __restrict__ sm,
                                              const float* __restrict__ WtA4,
                                              const float* __restrict__ WtB4,
                                              const float* __restrict__ biasWc,
                                              const float* __restrict__ b_ih,
                                              const float* __restrict__ b_hh,
                                              const int* __restrict__ gcnt) {
    __shared__ float ss[TM3 * 128];
    __shared__ float hsm[TM3 * 128];
    __shared__ float gA[TM3 * G3];
    __shared__ float gB[TM3 * 128];
    int tid = threadIdx.x;   // 0..383
    long rowBase = (long)blockIdx.x * TM3;
    if (tid < 256) {
        ((float4*)ss)[tid] = ((const float4*)(sm + rowBase * 128))[tid];
        ((float4*)hsm)[tid] = ((const float4*)(h + rowBase * 128))[tid];
    }
    __syncthreads();
    float ai[TM3], ah[TM3];
#pragma unroll
    for (int r = 0; r < TM3; r++) { ai[r] = 0.f; ah[r] = 0.f; }
    const float4* WA = (const float4*)WtA4;
    const float4* WB = (const float4*)WtB4;
#pragma unroll 2
    for (int k4 = 0; k4 < 32; k4++) {
        float4 wa = WA[k4 * G3 + tid];
        float4 wb = WB[k4 * G3 + tid];
#pragma unroll
        for (int r = 0; r < TM3; r++) {
            float4 sv = *((const float4*)&ss[r * 128 + k4 * 4]);
            float4 hv = *((const float4*)&hsm[r * 128 + k4 * 4]);
            ai[r] = fmaf(sv.x, wa.x, ai[r]);
            ai[r] = fmaf(sv.y, wa.y, ai[r]);
            ai[r] = fmaf(sv.z, wa.z, ai[r]);
            ai[r] = fmaf(sv.w, wa.w, ai[r]);
            ah[r] = fmaf(hv.x, wb.x, ah[r]);
            ah[r] = fmaf(hv.y, wb.y, ah[r]);
            ah[r] = fmaf(hv.z, wb.z, ah[r]);
            ah[r] = fmaf(hv.w, wb.w, ah[r]);
        }
    }
    float bWc = biasWc[tid];
    float bih = b_ih[tid];
    float bhh = b_hh[tid];
#pragma unroll
    for (int r = 0; r < TM3; r++) {
        int node = (int)((rowBase + r) % NN);
        float gi = ai[r] + (float)gcnt[node] * bWc + bih;
        float gh = ah[r] + bhh;
        if (tid < 256) {
            gA[r * G3 + tid] = gi + gh;
        } else {
            gA[r * G3 + tid] = gi;
            gB[r * 128 + (tid - 256)] = gh;
        }
    }
    __syncthreads();
    for (int it = tid; it < TM3 * 128; it += 384) {
        int r = it >> 7;
        int m = it & 127;
        float xr = gA[r * G3 + m];
        float xz = gA[r * G3 + 128 + m];
        float rg = 1.f / (1.f + __expf(-xr));
        float z = 1.f / (1.f + __expf(-xz));
        float npre = gA[r * G3 + 256 + m] + rg * gB[r * 128 + m];
        // overflow-safe tanh
        float ax = fabsf(npre);
        float e = __expf(-2.f * ax);
        float t = (1.f - e) / (1.f + e);
        float n = copysignf(t, npre);
        float ho = hsm[r * 128 + m];
        h[(rowBase + r) * 128 + m] = (1.f - z) * n + z * ho;
    }
}

// ---------------------------------------------------------------------------
// final_out: hid = relu(h @ W_o1.T + b_o1); out = hid @ W_o2.T + b_o2
// ---------------------------------------------------------------------------
#define TMF 16
__global__ __launch_bounds__(128) void final_out(const float* __restrict__ h,
                                                 const float* __restrict__ WtO1,
                                                 const float* __restrict__ b_o1,
                                                 const float* __restrict__ W_o2,
                                                 const float* __restrict__ b_o2,
                                                 float* __restrict__ out) {
    __shared__ float hs[TMF * 128];
    __shared__ float hid[TMF * 129];   // padded stride to kill bank conflicts
    int tid = threadIdx.x;   // 0..127
    long rowBase = (long)blockIdx.x * TMF;
    const float4* src = (const float4*)(h + rowBase * 128);
#pragma unroll
    for (int i = 0; i < 4; i++) ((float4*)hs)[tid + i * 128] = src[tid + i * 128];
    __syncthreads();
    float acc[TMF];
#pragma unroll
    for (int r = 0; r < TMF; r++) acc[r] = 0.f;
    const float4* W = (const float4*)WtO1;
#pragma unroll 2
    for (int k4 = 0; k4 < 32; k4++) {
        float4 w = W[k4 * 128 + tid];
#pragma unroll
        for (int r = 0; r < TMF; r++) {
            float4 hv = *((const float4*)&hs[r * 128 + k4 * 4]);
            acc[r] = fmaf(hv.x, w.x, acc[r]);
            acc[r] = fmaf(hv.y, w.y, acc[r]);
            acc[r] = fmaf(hv.z, w.z, acc[r]);
            acc[r] = fmaf(hv.w, w.w, acc[r]);
        }
    }
    float bo = b_o1[tid];
#pragma unroll
    for (int r = 0; r < TMF; r++) {
        float v = acc[r] + bo;
        hid[r * 129 + tid] = (v > 0.f) ? v : 0.f;
    }
    __syncthreads();
    for (int it = tid; it < TMF * 9; it += 128) {
        int r = it / 9;
        int q = it - r * 9;
        float acc2 = b_o2[q];
        for (int k = 0; k < 128; k++) acc2 += hid[r * 129 + k] * W_o2[q * 128 + k];
        out[(rowBase + r) * 9 + q] = acc2;
    }
}

// ---------------------------------------------------------------------------
extern "C" void kernel_launch(void* const* d_in, const int* in_sizes, int n_in,
                              void* d_out, int out_size, void* d_ws, size_t ws_size,
                              hipStream_t stream) {
    const float* x      = (const float*)d_in[0];
    const int* ei       = (const int*)d_in[1];     // harness passes ints as int32
    const float* W_in   = (const float*)d_in[2];
    const float* b_in   = (const float*)d_in[3];
    const float* W_m1   = (const float*)d_in[4];
    const float* b_m1   = (const float*)d_in[5];
    const float* W_m2   = (const float*)d_in[6];
    const float* b_m2   = (const float*)d_in[7];
    const float* W_ih   = (const float*)d_in[8];
    const float* W_hh   = (const float*)d_in[9];
    const float* b_ih   = (const float*)d_in[10];
    const float* b_hh   = (const float*)d_in[11];
    const float* W_o1   = (const float*)d_in[12];
    const float* b_o1   = (const float*)d_in[13];
    const float* W_o2   = (const float*)d_in[14];
    const float* b_o2   = (const float*)d_in[15];
    float* out = (float*)d_out;

    char* ws = (char*)d_ws;
    size_t off = 0;
    auto alloc = [&](size_t bytes) -> char* {
        char* p = ws + off;
        off += (bytes + 255) & ~(size_t)255;
        return p;
    };
    float* h    = (float*)alloc((size_t)RR * HH * 4);      // 42.5 MB
    float* hAB  = (float*)alloc((size_t)RR * 256 * 4);     // 85 MB
    float* sm   = (float*)alloc((size_t)RR * MM * 4);      // 42.5 MB
    float* WtK1 = (float*)alloc(128 * 256 * 4);
    float* WtA4 = (float*)alloc(128 * G3 * 4);
    float* WtB4 = (float*)alloc(128 * G3 * 4);
    float* WtO1 = (float*)alloc(128 * 128 * 4);
    float* biasWc = (float*)alloc(512 * 4);
    int* goff  = (int*)alloc(128 * 4);
    int* gcnt  = (int*)alloc(128 * 4);
    int* gsend = (int*)alloc(2048 * 4);

    prep_graph<<<1, 128, 0, stream>>>(ei, goff, gcnt, gsend);
    prep_wc<<<(G3 * HH + 255) / 256, 256, 0, stream>>>(W_ih, W_m2, b_m2, WtA4, biasWc);
    prep_trans<<<192, 256, 0, stream>>>(W_m1, W_hh, W_o1, WtK1, WtB4, WtO1);
    input_proj<<<(RR * HH) / 256, 256, 0, stream>>>(x, W_in, b_in, h);

    for (int s = 0; s < NSTEPS; s++) {
        k1_gemm<<<RR / TM1, 256, 0, stream>>>(h, WtK1, b_m1, hAB);
        k2_edges<<<RR, 128, 0, stream>>>(hAB, goff, gsend, sm);
        k3_gru<<<RR / TM3, 384, 0, stream>>>(h, sm, WtA4, WtB4, biasWc, b_ih, b_hh, gcnt);
    }
    final_out<<<RR / TMF, 128, 0, stream>>>(h, WtO1, b_o1, W_o2, b_o2, out);
}

// Round 4
// 4807.921 us; speedup vs baseline: 1.0597x; 1.0597x over previous
//
#include <hip/hip_runtime.h>

#define BB 1024
#define NN 81
#define EE 1620
#define HH 128
#define G3 384
#define NSTEPS 8

#define RSTR 96      // hT/smT row stride (floats); rows 0..80 valid, ..95 pad
#define ABSTR 260    // hAB row stride (floats), 81 rows x 256 used cols

typedef __attribute__((ext_vector_type(4))) float f32x4;

// ---- LDS float offsets ----
#define F_HT    0            // 128*96 = 12288  : hT[k][r] = h[r][k]
#define F_R2    12288        // 21060 floats    : union{ xs(810)+win(1280) | hAB 81x260 | smT 128x96 | hid 81x132 }
#define F_GOFF  33348        // 82 ints
#define F_GSEND 33430        // 1620 ushorts (810 float slots)
#define F_BM1   34240        // 128
#define F_BASE  34368        // 512
#define F_EXT   34880        // 512
#define F_TOT   35392
#define LDS_BYTES (F_TOT * 4)   // 141568 bytes

#define HIDSTR 132

// ---------------------------------------------------------------------------
// prep_graph: CSR by receiver (int32 edge input) — verified in R2.
// ---------------------------------------------------------------------------
__global__ __launch_bounds__(128) void prep_graph(const int* __restrict__ ei,
                                                  int* __restrict__ goff,
                                                  int* __restrict__ gsend) {
    __shared__ int eis[2 * EE];
    __shared__ int cs[NN];
    __shared__ int offs[NN + 1];
    int tid = threadIdx.x;
    for (int i = tid; i < 2 * EE; i += 128) eis[i] = ei[i];
    __syncthreads();
    if (tid < NN) {
        int c = 0;
        for (int e = 0; e < EE; e++) if (eis[EE + e] == tid) c++;
        cs[tid] = c;
    }
    __syncthreads();
    if (tid == 0) {
        int o = 0;
        for (int r = 0; r < NN; r++) { offs[r] = o; o += cs[r]; }
        offs[NN] = o;
    }
    __syncthreads();
    if (tid < NN) {
        int pos = offs[tid];
        for (int e = 0; e < EE; e++) {
            if (eis[EE + e] == tid) gsend[pos++] = eis[e];
        }
        goff[tid] = offs[tid];
    }
    if (tid == 0) goff[NN] = offs[NN];
}

// ---------------------------------------------------------------------------
// prep_wc: Wc[c][o] = sum_m W_ih[c][m] * W_m2[m][o]   (384 x 128)
// ---------------------------------------------------------------------------
__global__ __launch_bounds__(256) void prep_wc(const float* __restrict__ W_ih,
                                               const float* __restrict__ W_m2,
                                               float* __restrict__ Wc) {
    int idx = blockIdx.x * 256 + threadIdx.x;
    if (idx >= G3 * HH) return;
    int c = idx >> 7, o = idx & 127;
    float acc = 0.f;
    for (int m = 0; m < HH; m++) acc += W_ih[c * HH + m] * W_m2[m * HH + o];
    Wc[idx] = acc;
}

// ---------------------------------------------------------------------------
// prep_bias: base[512], ext[512]
//  c<256 : base=b_ih[c]+b_hh[c], ext=(W_ih@b_m2)[c]
//  256..383: base=b_ih[c],       ext=(W_ih@b_m2)[c]
//  384..511: base=b_hh[c-128],   ext=0
// ---------------------------------------------------------------------------
__global__ __launch_bounds__(256) void prep_bias(const float* __restrict__ W_ih,
                                                 const float* __restrict__ b_m2,
                                                 const float* __restrict__ b_ih,
                                                 const float* __restrict__ b_hh,
                                                 float* __restrict__ basev,
                                                 float* __restrict__ extv) {
    int c = blockIdx.x * 256 + threadIdx.x;
    if (c >= 512) return;
    float base, ext;
    if (c < 384) {
        float bwc = 0.f;
        for (int m = 0; m < HH; m++) bwc += W_ih[c * HH + m] * b_m2[m];
        ext = bwc;
        base = (c < 256) ? (b_ih[c] + b_hh[c]) : b_ih[c];
    } else {
        ext = 0.f;
        base = b_hh[c - 128];
    }
    basev[c] = base;
    extv[c] = ext;
}

// ---------------------------------------------------------------------------
// prep_w1t: W1t[k][c] (128 x 256): c<128 -> W_m1[c][k] ; else W_m1[c-128][128+k]
// ---------------------------------------------------------------------------
__global__ __launch_bounds__(256) void prep_w1t(const float* __restrict__ W_m1,
                                                float* __restrict__ W1t) {
    int idx = blockIdx.x * 256 + threadIdx.x;   // 128*256
    if (idx >= 128 * 256) return;
    int k = idx >> 8, c = idx & 255;
    W1t[idx] = (c < 128) ? W_m1[c * 256 + k] : W_m1[(c - 128) * 256 + 128 + k];
}

// ---------------------------------------------------------------------------
// prep_wg: Wg[ph][k][c] (2 x 128 x 384): ph0 = Wc[c][k], ph1 = W_hh[c][k]
// ---------------------------------------------------------------------------
__global__ __launch_bounds__(256) void prep_wg(const float* __restrict__ Wc,
                                               const float* __restrict__ W_hh,
                                               float* __restrict__ Wg) {
    int idx = blockIdx.x * 256 + threadIdx.x;   // 2*128*384 = 98304
    if (idx >= 2 * 128 * G3) return;
    int ph = idx / (128 * G3);
    int rem = idx - ph * (128 * G3);
    int k = rem / G3;
    int c = rem - k * G3;
    Wg[idx] = ph ? W_hh[c * HH + k] : Wc[c * HH + k];
}

// ---------------------------------------------------------------------------
// prep_wo1t: Wo1t[k][c] = W_o1[c][k]   (128 x 128)
// ---------------------------------------------------------------------------
__global__ __launch_bounds__(256) void prep_wo1t(const float* __restrict__ W_o1,
                                                 float* __restrict__ Wo1t) {
    int idx = blockIdx.x * 256 + threadIdx.x;
    if (idx >= 128 * 128) return;
    int k = idx >> 7, c = idx & 127;
    Wo1t[idx] = W_o1[c * HH + k];
}

// ---------------------------------------------------------------------------
// fused_rrn: one workgroup per puzzle, fp32 throughout.
// thread map: rW = t&31 (rows rW, rW+32, rW+64), q = t>>5 (0..15)
// ---------------------------------------------------------------------------
__global__ __launch_bounds__(512, 2) void fused_rrn(
    const float* __restrict__ x,
    const float* __restrict__ W_in, const float* __restrict__ b_in,
    const float* __restrict__ b_m1,
    const float* __restrict__ W1t, const float* __restrict__ Wg,
    const float* __restrict__ basev, const float* __restrict__ extv,
    const float* __restrict__ Wo1t, const float* __restrict__ b_o1,
    const float* __restrict__ W_o2, const float* __restrict__ b_o2,
    const int* __restrict__ goff_g, const int* __restrict__ gsend_g,
    float* __restrict__ out)
{
    extern __shared__ float smf[];
    float* hT   = smf + F_HT;
    float* reg2 = smf + F_R2;          // hAB | smT | xs+win | hid
    int*   goffL = (int*)(smf + F_GOFF);
    unsigned short* gsendL = (unsigned short*)(smf + F_GSEND);
    float* bm1L  = smf + F_BM1;
    float* baseL = smf + F_BASE;
    float* extL  = smf + F_EXT;

    const int t  = threadIdx.x;
    const int b  = blockIdx.x;
    const int rW = t & 31;
    const int q  = t >> 5;
    const int r0 = rW, r1 = rW + 32, r2 = rW + 64;

    // ---- stage misc + x/W_in (x/W_in into reg2, used once) ----
    float* xsL  = reg2;          // 810
    float* winL = reg2 + 810;    // 1280
    for (int i = t; i < NN + 1; i += 512) goffL[i] = goff_g[i];
    for (int i = t; i < EE; i += 512) gsendL[i] = (unsigned short)gsend_g[i];
    baseL[t] = basev[t];
    extL[t]  = extv[t];
    if (t < 128) bm1L[t] = b_m1[t];
    for (int i = t; i < NN * 10; i += 512) xsL[i] = x[(long)b * (NN * 10) + i];
    for (int i = t; i < HH * 10; i += 512) winL[i] = W_in[i];
    __syncthreads();

    // ---- input projection: hT[m][r] = x[r]@W_in[m] + b_in[m] ----
#pragma unroll
    for (int s = 0; s < 3; s++) {
        int row = rW + 32 * s;
        if (row < NN) {
#pragma unroll
            for (int j = 0; j < 8; j++) {
                int m = 8 * q + j;
                float acc = b_in[m];
#pragma unroll
                for (int k = 0; k < 10; k++) acc += xsL[row * 10 + k] * winL[m * 10 + k];
                hT[m * RSTR + row] = acc;
            }
        }
    }
    __syncthreads();

    // ======================= 8 message-passing steps =======================
    for (int step = 0; step < NSTEPS; step++) {
        // ---------- GEMM1: hAB = h @ W1^T (+ b_m1 on cols>=128) ----------
        {
            float acc[3][16];
#pragma unroll
            for (int s = 0; s < 3; s++)
#pragma unroll
                for (int i = 0; i < 16; i++) acc[s][i] = 0.f;
            const float* Bb = W1t + 16 * q;
#pragma unroll 2
            for (int k = 0; k < 128; k++) {
                float a0v = hT[k * RSTR + r0];
                float a1v = hT[k * RSTR + r1];
                float a2v = hT[k * RSTR + r2];
                const float* Bk = Bb + k * 256;
                f32x4 b0 = *(const f32x4*)(Bk);
                f32x4 b1 = *(const f32x4*)(Bk + 4);
                f32x4 b2 = *(const f32x4*)(Bk + 8);
                f32x4 b3 = *(const f32x4*)(Bk + 12);
#pragma unroll
                for (int j = 0; j < 4; j++) {
                    acc[0][j]      = fmaf(a0v, b0[j], acc[0][j]);
                    acc[0][4 + j]  = fmaf(a0v, b1[j], acc[0][4 + j]);
                    acc[0][8 + j]  = fmaf(a0v, b2[j], acc[0][8 + j]);
                    acc[0][12 + j] = fmaf(a0v, b3[j], acc[0][12 + j]);
                    acc[1][j]      = fmaf(a1v, b0[j], acc[1][j]);
                    acc[1][4 + j]  = fmaf(a1v, b1[j], acc[1][4 + j]);
                    acc[1][8 + j]  = fmaf(a1v, b2[j], acc[1][8 + j]);
                    acc[1][12 + j] = fmaf(a1v, b3[j], acc[1][12 + j]);
                    acc[2][j]      = fmaf(a2v, b0[j], acc[2][j]);
                    acc[2][4 + j]  = fmaf(a2v, b1[j], acc[2][4 + j]);
                    acc[2][8 + j]  = fmaf(a2v, b2[j], acc[2][8 + j]);
                    acc[2][12 + j] = fmaf(a2v, b3[j], acc[2][12 + j]);
                }
            }
            // bias for recv half
            float bias[16];
#pragma unroll
            for (int i = 0; i < 16; i++) {
                int c = 16 * q + i;
                bias[i] = (c >= 128) ? bm1L[c - 128] : 0.f;
            }
#pragma unroll
            for (int s = 0; s < 3; s++) {
                int row = rW + 32 * s;
                if (row < NN) {
                    float* dst = reg2 + row * ABSTR + 16 * q;
#pragma unroll
                    for (int i = 0; i < 16; i++) dst[i] = acc[s][i] + bias[i];
                }
            }
        }
        __syncthreads();   // B1: hAB ready

        // ---------- edge aggregation: sm[r][m] = sum_e relu(hA[s]+hB'[r]) ----------
        float sv[3][8];
        {
#pragma unroll
            for (int s = 0; s < 3; s++) {
                int row = rW + 32 * s;
                if (row >= NN) continue;
                int e0 = goffL[row], e1 = goffL[row + 1];
                const float* hbP = reg2 + row * ABSTR + 128 + 8 * q;
                float hb[8], ac[8];
#pragma unroll
                for (int j = 0; j < 8; j++) { hb[j] = hbP[j]; ac[j] = 0.f; }
                for (int e = e0; e < e1; e++) {
                    int sn = gsendL[e];
                    const float* avP = reg2 + sn * ABSTR + 8 * q;
#pragma unroll
                    for (int j = 0; j < 8; j++) {
                        float p = avP[j] + hb[j];
                        ac[j] += fmaxf(p, 0.f);
                    }
                }
#pragma unroll
                for (int j = 0; j < 8; j++) sv[s][j] = ac[j];
            }
        }
        __syncthreads();   // B2: all hAB reads done, reg2 free for smT
        {
            float* smT = reg2;
#pragma unroll
            for (int s = 0; s < 3; s++) {
                int row = rW + 32 * s;
                if (row >= NN) continue;
#pragma unroll
                for (int j = 0; j < 8; j++) smT[(8 * q + j) * RSTR + row] = sv[s][j];
            }
        }
        __syncthreads();   // B3: smT ready

        // ---------- GEMM2: gates from [sm | h] ----------
        {
            float rr[3][8], zz[3][8], gn[3][8], hh[3][8];
#pragma unroll
            for (int s = 0; s < 3; s++)
#pragma unroll
                for (int j = 0; j < 8; j++) { rr[s][j] = 0.f; zz[s][j] = 0.f; gn[s][j] = 0.f; hh[s][j] = 0.f; }

            const float* smT = reg2;

#define G2_PHASE(At, Bbase, NACC)                                          \
            {                                                              \
                _Pragma("unroll 2")                                        \
                for (int k = 0; k < 128; k++) {                            \
                    float a0v = (At)[k * RSTR + r0];                       \
                    float a1v = (At)[k * RSTR + r1];                       \
                    float a2v = (At)[k * RSTR + r2];                       \
                    const float* Bk = (Bbase) + k * G3 + 8 * q;            \
                    f32x4 br0 = *(const f32x4*)(Bk);                       \
                    f32x4 br1 = *(const f32x4*)(Bk + 4);                   \
                    f32x4 bz0 = *(const f32x4*)(Bk + 128);                 \
                    f32x4 bz1 = *(const f32x4*)(Bk + 132);                 \
                    f32x4 bn0 = *(const f32x4*)(Bk + 256);                 \
                    f32x4 bn1 = *(const f32x4*)(Bk + 260);                 \
                    _Pragma("unroll")                                      \
                    for (int j = 0; j < 4; j++) {                          \
                        rr[0][j]     = fmaf(a0v, br0[j], rr[0][j]);        \
                        rr[0][4 + j] = fmaf(a0v, br1[j], rr[0][4 + j]);    \
                        zz[0][j]     = fmaf(a0v, bz0[j], zz[0][j]);        \
                        zz[0][4 + j] = fmaf(a0v, bz1[j], zz[0][4 + j]);    \
                        NACC[0][j]     = fmaf(a0v, bn0[j], NACC[0][j]);    \
                        NACC[0][4 + j] = fmaf(a0v, bn1[j], NACC[0][4 + j]);\
                        rr[1][j]     = fmaf(a1v, br0[j], rr[1][j]);        \
                        rr[1][4 + j] = fmaf(a1v, br1[j], rr[1][4 + j]);    \
                        zz[1][j]     = fmaf(a1v, bz0[j], zz[1][j]);        \
                        zz[1][4 + j] = fmaf(a1v, bz1[j], zz[1][4 + j]);    \
                        NACC[1][j]     = fmaf(a1v, bn0[j], NACC[1][j]);    \
                        NACC[1][4 + j] = fmaf(a1v, bn1[j], NACC[1][4 + j]);\
                        rr[2][j]     = fmaf(a2v, br0[j], rr[2][j]);        \
                        rr[2][4 + j] = fmaf(a2v, br1[j], rr[2][4 + j]);    \
                        zz[2][j]     = fmaf(a2v, bz0[j], zz[2][j]);        \
                        zz[2][4 + j] = fmaf(a2v, bz1[j], zz[2][4 + j]);    \
                        NACC[2][j]     = fmaf(a2v, bn0[j], NACC[2][j]);    \
                        NACC[2][4 + j] = fmaf(a2v, bn1[j], NACC[2][4 + j]);\
                    }                                                      \
                }                                                          \
            }

            G2_PHASE(smT, Wg, gn)                 // gi parts
            G2_PHASE(hT, Wg + 128 * G3, hh)       // gh parts
#undef G2_PHASE

            __syncthreads();   // B4: all smT/hT reads done

            // ---- GRU epilogue ----
            float b0v[8], e0v[8], b1v[8], e1v[8], b2v[8], e2v[8], b3v[8];
#pragma unroll
            for (int j = 0; j < 8; j++) {
                int m = 8 * q + j;
                b0v[j] = baseL[m];        e0v[j] = extL[m];
                b1v[j] = baseL[128 + m];  e1v[j] = extL[128 + m];
                b2v[j] = baseL[256 + m];  e2v[j] = extL[256 + m];
                b3v[j] = baseL[384 + m];
            }
#pragma unroll
            for (int s = 0; s < 3; s++) {
                int row = rW + 32 * s;
                if (row >= NN) continue;
                float cf = (float)(goffL[row + 1] - goffL[row]);
#pragma unroll
                for (int j = 0; j < 8; j++) {
                    int m = 8 * q + j;
                    float g0 = rr[s][j] + b0v[j] + cf * e0v[j];
                    float g1 = zz[s][j] + b1v[j] + cf * e1v[j];
                    float g2 = gn[s][j] + b2v[j] + cf * e2v[j];
                    float g3 = hh[s][j] + b3v[j];
                    float rg_ = 1.f / (1.f + __expf(-g0));
                    float z   = 1.f / (1.f + __expf(-g1));
                    float npre = g2 + rg_ * g3;
                    float ax = fabsf(npre);
                    float e  = __expf(-2.f * ax);
                    float tt = (1.f - e) / (1.f + e);
                    float n  = copysignf(tt, npre);
                    float ho = hT[m * RSTR + row];
                    float hn = (1.f - z) * n + z * ho;
                    hT[m * RSTR + row] = hn;
                }
            }
        }
        __syncthreads();   // B5: new h visible
    }

    // ======================= output head =======================
    // hid = relu(h @ W_o1^T + b_o1) -> reg2 (stride 132)
    {
        float acc[3][8];
#pragma unroll
        for (int s = 0; s < 3; s++)
#pragma unroll
            for (int j = 0; j < 8; j++) acc[s][j] = 0.f;
        const float* Bb = Wo1t + 8 * q;
#pragma unroll 2
        for (int k = 0; k < 128; k++) {
            float a0v = hT[k * RSTR + r0];
            float a1v = hT[k * RSTR + r1];
            float a2v = hT[k * RSTR + r2];
            const float* Bk = Bb + k * 128;
            f32x4 b0 = *(const f32x4*)(Bk);
            f32x4 b1 = *(const f32x4*)(Bk + 4);
#pragma unroll
            for (int j = 0; j < 4; j++) {
                acc[0][j]     = fmaf(a0v, b0[j], acc[0][j]);
                acc[0][4 + j] = fmaf(a0v, b1[j], acc[0][4 + j]);
                acc[1][j]     = fmaf(a1v, b0[j], acc[1][j]);
                acc[1][4 + j] = fmaf(a1v, b1[j], acc[1][4 + j]);
                acc[2][j]     = fmaf(a2v, b0[j], acc[2][j]);
                acc[2][4 + j] = fmaf(a2v, b1[j], acc[2][4 + j]);
            }
        }
        float bo[8];
#pragma unroll
        for (int j = 0; j < 8; j++) bo[j] = b_o1[8 * q + j];
        __syncthreads();   // hT reads done; reg2 (smT) dead -> hid
#pragma unroll
        for (int s = 0; s < 3; s++) {
            int row = rW + 32 * s;
            if (row < NN) {
                float* dst = reg2 + row * HIDSTR + 8 * q;
#pragma unroll
                for (int j = 0; j < 8; j++) dst[j] = fmaxf(acc[s][j] + bo[j], 0.f);
            }
        }
    }
    __syncthreads();
    // stage W_o2/b_o2 into hT area (hT dead)
    {
        float* wo2L = hT;           // 1152
        float* bo2L = hT + 1152;    // 9
        for (int i = t; i < 9 * HH; i += 512) wo2L[i] = W_o2[i];
        if (t < 9) bo2L[t] = b_o2[t];
    }
    __syncthreads();
    {
        const float* wo2L = hT;
        const float* bo2L = hT + 1152;
        for (int idx = t; idx < NN * 9; idx += 512) {
            int r = idx / 9, qq = idx - 9 * r;
            float acc = bo2L[qq];
            const float* hrow = reg2 + r * HIDSTR;
            const float* wrow = wo2L + qq * HH;
            for (int k = 0; k < HH; k++) acc = fmaf(hrow[k], wrow[k], acc);
            out[((long)b * NN + r) * 9 + qq] = acc;
        }
    }
}

// ---------------------------------------------------------------------------
extern "C" void kernel_launch(void* const* d_in, const int* in_sizes, int n_in,
                              void* d_out, int out_size, void* d_ws, size_t ws_size,
                              hipStream_t stream) {
    const float* x      = (const float*)d_in[0];
    const int* ei       = (const int*)d_in[1];
    const float* W_in   = (const float*)d_in[2];
    const float* b_in   = (const float*)d_in[3];
    const float* W_m1   = (const float*)d_in[4];
    const float* b_m1   = (const float*)d_in[5];
    const float* W_m2   = (const float*)d_in[6];
    const float* b_m2   = (const float*)d_in[7];
    const float* W_ih   = (const float*)d_in[8];
    const float* W_hh   = (const float*)d_in[9];
    const float* b_ih   = (const float*)d_in[10];
    const float* b_hh   = (const float*)d_in[11];
    const float* W_o1   = (const float*)d_in[12];
    const float* b_o1   = (const float*)d_in[13];
    const float* W_o2   = (const float*)d_in[14];
    const float* b_o2   = (const float*)d_in[15];
    float* out = (float*)d_out;

    char* ws = (char*)d_ws;
    size_t off = 0;
    auto alloc = [&](size_t bytes) -> char* {
        char* p = ws + off;
        off += (bytes + 255) & ~(size_t)255;
        return p;
    };
    float* Wc    = (float*)alloc((size_t)G3 * HH * 4);      // 196608
    float* W1t   = (float*)alloc(128 * 256 * 4);            // 131072
    float* Wg    = (float*)alloc(2 * 128 * G3 * 4);         // 393216
    float* Wo1t  = (float*)alloc(128 * 128 * 4);            // 65536
    float* basev = (float*)alloc(512 * 4);
    float* extv  = (float*)alloc(512 * 4);
    int* goff    = (int*)alloc((NN + 1) * 4);
    int* gsend   = (int*)alloc(EE * 4);

    prep_graph<<<1, 128, 0, stream>>>(ei, goff, gsend);
    prep_wc<<<(G3 * HH + 255) / 256, 256, 0, stream>>>(W_ih, W_m2, Wc);
    prep_bias<<<2, 256, 0, stream>>>(W_ih, b_m2, b_ih, b_hh, basev, extv);
    prep_w1t<<<128, 256, 0, stream>>>(W_m1, W1t);
    prep_wg<<<384, 256, 0, stream>>>(Wc, W_hh, Wg);
    prep_wo1t<<<64, 256, 0, stream>>>(W_o1, Wo1t);

    (void)hipFuncSetAttribute((const void*)fused_rrn,
                              hipFuncAttributeMaxDynamicSharedMemorySize,
                              (int)LDS_BYTES);
    fused_rrn<<<BB, 512, LDS_BYTES, stream>>>(
        x, W_in, b_in, b_m1, W1t, Wg, basev, extv,
        Wo1t, b_o1, W_o2, b_o2, goff, gsend, out);
}

// Round 5
// 4470.689 us; speedup vs baseline: 1.1397x; 1.0754x over previous
//
#include <hip/hip_runtime.h>

#define BB 1024
#define NN 81
#define EE 1620
#define HH 128
#define G3 384
#define NSTEPS 8

#define RSTR 96      // hT/smT row stride (floats)
#define ABSTR 260    // hAB row stride (floats)
#define HIDSTR 132

typedef __attribute__((ext_vector_type(4))) float f32x4;

// ---- LDS float offsets ----
#define F_HT    0            // 128*96 = 12288 : hT[k][r] = h[r][k]
#define F_R2    12288        // 21060 floats   : union{ xs+win | hAB 81x260 | smT 128x96 | hid 81x132 }
#define F_GOFF  33348        // 82 ints
#define F_GSEND 33430        // 1620 ushorts (810 float slots)
#define F_BM1   34240        // 128
#define F_BASE  34368        // 512
#define F_EXT   34880        // 512
#define F_TOT   35392
#define LDS_BYTES (F_TOT * 4)   // 141568 bytes

// ---------------------------------------------------------------------------
// prep_graph: CSR by receiver (int32 edge input) — verified R2/R4.
// ---------------------------------------------------------------------------
__global__ __launch_bounds__(128) void prep_graph(const int* __restrict__ ei,
                                                  int* __restrict__ goff,
                                                  int* __restrict__ gsend) {
    __shared__ int eis[2 * EE];
    __shared__ int cs[NN];
    __shared__ int offs[NN + 1];
    int tid = threadIdx.x;
    for (int i = tid; i < 2 * EE; i += 128) eis[i] = ei[i];
    __syncthreads();
    if (tid < NN) {
        int c = 0;
        for (int e = 0; e < EE; e++) if (eis[EE + e] == tid) c++;
        cs[tid] = c;
    }
    __syncthreads();
    if (tid == 0) {
        int o = 0;
        for (int r = 0; r < NN; r++) { offs[r] = o; o += cs[r]; }
        offs[NN] = o;
    }
    __syncthreads();
    if (tid < NN) {
        int pos = offs[tid];
        for (int e = 0; e < EE; e++) {
            if (eis[EE + e] == tid) gsend[pos++] = eis[e];
        }
        goff[tid] = offs[tid];
    }
    if (tid == 0) goff[NN] = offs[NN];
}

// ---------------------------------------------------------------------------
// prep_wc: Wc[c][o] = sum_m W_ih[c][m] * W_m2[m][o]   (384 x 128)
// ---------------------------------------------------------------------------
__global__ __launch_bounds__(256) void prep_wc(const float* __restrict__ W_ih,
                                               const float* __restrict__ W_m2,
                                               float* __restrict__ Wc) {
    int idx = blockIdx.x * 256 + threadIdx.x;
    if (idx >= G3 * HH) return;
    int c = idx >> 7, o = idx & 127;
    float acc = 0.f;
    for (int m = 0; m < HH; m++) acc += W_ih[c * HH + m] * W_m2[m * HH + o];
    Wc[idx] = acc;
}

// ---------------------------------------------------------------------------
// prep_bias: base[512], ext[512]
// ---------------------------------------------------------------------------
__global__ __launch_bounds__(256) void prep_bias(const float* __restrict__ W_ih,
                                                 const float* __restrict__ b_m2,
                                                 const float* __restrict__ b_ih,
                                                 const float* __restrict__ b_hh,
                                                 float* __restrict__ basev,
                                                 float* __restrict__ extv) {
    int c = blockIdx.x * 256 + threadIdx.x;
    if (c >= 512) return;
    float base, ext;
    if (c < 384) {
        float bwc = 0.f;
        for (int m = 0; m < HH; m++) bwc += W_ih[c * HH + m] * b_m2[m];
        ext = bwc;
        base = (c < 256) ? (b_ih[c] + b_hh[c]) : b_ih[c];
    } else {
        ext = 0.f;
        base = b_hh[c - 128];
    }
    basev[c] = base;
    extv[c] = ext;
}

// ---------------------------------------------------------------------------
// prep_w1t: W1t[k][c] (128 x 256)
// ---------------------------------------------------------------------------
__global__ __launch_bounds__(256) void prep_w1t(const float* __restrict__ W_m1,
                                                float* __restrict__ W1t) {
    int idx = blockIdx.x * 256 + threadIdx.x;
    if (idx >= 128 * 256) return;
    int k = idx >> 8, c = idx & 255;
    W1t[idx] = (c < 128) ? W_m1[c * 256 + k] : W_m1[(c - 128) * 256 + 128 + k];
}

// ---------------------------------------------------------------------------
// prep_wg: Wg[ph][k][c] (2 x 128 x 384): ph0 = Wc[c][k], ph1 = W_hh[c][k]
// ---------------------------------------------------------------------------
__global__ __launch_bounds__(256) void prep_wg(const float* __restrict__ Wc,
                                               const float* __restrict__ W_hh,
                                               float* __restrict__ Wg) {
    int idx = blockIdx.x * 256 + threadIdx.x;
    if (idx >= 2 * 128 * G3) return;
    int ph = idx / (128 * G3);
    int rem = idx - ph * (128 * G3);
    int k = rem / G3;
    int c = rem - k * G3;
    Wg[idx] = ph ? W_hh[c * HH + k] : Wc[c * HH + k];
}

// ---------------------------------------------------------------------------
// prep_wo1t: Wo1t[k][c] = W_o1[c][k]   (128 x 128)
// ---------------------------------------------------------------------------
__global__ __launch_bounds__(256) void prep_wo1t(const float* __restrict__ W_o1,
                                                 float* __restrict__ Wo1t) {
    int idx = blockIdx.x * 256 + threadIdx.x;
    if (idx >= 128 * 128) return;
    int k = idx >> 7, c = idx & 127;
    Wo1t[idx] = W_o1[c * HH + k];
}

// ---------------------------------------------------------------------------
// fused_rrn: one workgroup per puzzle, 1024 threads (16 waves), fp32.
// thread map: rW = t&31 (rows rW, rW+32, rW+64), q = t>>5 (0..31, feat quad 4q)
// ---------------------------------------------------------------------------
__global__ __launch_bounds__(1024) void fused_rrn(
    const float* __restrict__ x,
    const float* __restrict__ W_in, const float* __restrict__ b_in,
    const float* __restrict__ b_m1,
    const float* __restrict__ W1t, const float* __restrict__ Wg,
    const float* __restrict__ basev, const float* __restrict__ extv,
    const float* __restrict__ Wo1t, const float* __restrict__ b_o1,
    const float* __restrict__ W_o2, const float* __restrict__ b_o2,
    const int* __restrict__ goff_g, const int* __restrict__ gsend_g,
    float* __restrict__ out)
{
    extern __shared__ float smf[];
    float* hT   = smf + F_HT;
    float* reg2 = smf + F_R2;
    int*   goffL = (int*)(smf + F_GOFF);
    unsigned short* gsendL = (unsigned short*)(smf + F_GSEND);
    float* bm1L  = smf + F_BM1;
    float* baseL = smf + F_BASE;
    float* extL  = smf + F_EXT;

    const int t  = threadIdx.x;
    const int b  = blockIdx.x;
    const int rW = t & 31;
    const int q  = t >> 5;            // 0..31
    const int r0 = rW, r1 = rW + 32, r2 = rW + 64;
    const int fq = 4 * q;             // feature quad base

    // ---- stage misc + x/W_in (into reg2; used once) ----
    float* xsL  = reg2;          // 810
    float* winL = reg2 + 810;    // 1280
    for (int i = t; i < NN + 1; i += 1024) goffL[i] = goff_g[i];
    for (int i = t; i < EE; i += 1024) gsendL[i] = (unsigned short)gsend_g[i];
    if (t < 512) { baseL[t] = basev[t]; extL[t] = extv[t]; }
    if (t < 128) bm1L[t] = b_m1[t];
    for (int i = t; i < NN * 10; i += 1024) xsL[i] = x[(long)b * (NN * 10) + i];
    for (int i = t; i < HH * 10; i += 1024) winL[i] = W_in[i];
    __syncthreads();

    // ---- input projection: hT[m][r] ----
    for (int idx = t; idx < NN * HH; idx += 1024) {
        int r = idx >> 7, m = idx & 127;
        float acc = b_in[m];
#pragma unroll
        for (int k = 0; k < 10; k++) acc += xsL[r * 10 + k] * winL[m * 10 + k];
        hT[m * RSTR + r] = acc;
    }
    __syncthreads();

    // ======================= 8 message-passing steps =======================
    for (int step = 0; step < NSTEPS; step++) {
        // ---------- GEMM1: hAB = h @ W1^T (raw, bias added in edge phase) ----------
        {
            float acc[3][8];
#pragma unroll
            for (int s = 0; s < 3; s++)
#pragma unroll
                for (int i = 0; i < 8; i++) acc[s][i] = 0.f;
            const float* Bb = W1t + 8 * q;
#pragma unroll 4
            for (int k = 0; k < 128; k++) {
                float a0v = hT[k * RSTR + r0];
                float a1v = hT[k * RSTR + r1];
                float a2v = hT[k * RSTR + r2];
                const float* Bk = Bb + k * 256;
                f32x4 b0 = *(const f32x4*)(Bk);
                f32x4 b1 = *(const f32x4*)(Bk + 4);
#pragma unroll
                for (int j = 0; j < 4; j++) {
                    acc[0][j]     = fmaf(a0v, b0[j], acc[0][j]);
                    acc[0][4 + j] = fmaf(a0v, b1[j], acc[0][4 + j]);
                    acc[1][j]     = fmaf(a1v, b0[j], acc[1][j]);
                    acc[1][4 + j] = fmaf(a1v, b1[j], acc[1][4 + j]);
                    acc[2][j]     = fmaf(a2v, b0[j], acc[2][j]);
                    acc[2][4 + j] = fmaf(a2v, b1[j], acc[2][4 + j]);
                }
            }
#pragma unroll
            for (int s = 0; s < 3; s++) {
                int row = rW + 32 * s;
                if (row < NN) {
                    float* dst = reg2 + row * ABSTR + 8 * q;
                    *(f32x4*)(dst)     = *(const f32x4*)(&acc[s][0]);
                    *(f32x4*)(dst + 4) = *(const f32x4*)(&acc[s][4]);
                }
            }
        }
        __syncthreads();   // B1: hAB ready

        // ---------- edge aggregation (feature quad fq per lane) ----------
        float sv[3][4];
        {
            float bq[4];
#pragma unroll
            for (int j = 0; j < 4; j++) bq[j] = bm1L[fq + j];
#pragma unroll
            for (int s = 0; s < 3; s++) {
                int row = rW + 32 * s;
                if (row >= NN) { sv[s][0] = sv[s][1] = sv[s][2] = sv[s][3] = 0.f; continue; }
                int e0 = goffL[row], e1 = goffL[row + 1];
                f32x4 hb = *(const f32x4*)(reg2 + row * ABSTR + 128 + fq);
                float hbb[4], ac[4];
#pragma unroll
                for (int j = 0; j < 4; j++) { hbb[j] = hb[j] + bq[j]; ac[j] = 0.f; }
                for (int e = e0; e < e1; e++) {
                    int sn = gsendL[e];
                    f32x4 av = *(const f32x4*)(reg2 + sn * ABSTR + fq);
#pragma unroll
                    for (int j = 0; j < 4; j++) ac[j] += fmaxf(av[j] + hbb[j], 0.f);
                }
#pragma unroll
                for (int j = 0; j < 4; j++) sv[s][j] = ac[j];
            }
        }
        __syncthreads();   // B2: hAB reads done, reg2 reusable as smT
        {
            float* smT = reg2;
#pragma unroll
            for (int s = 0; s < 3; s++) {
                int row = rW + 32 * s;
                if (row >= NN) continue;
#pragma unroll
                for (int j = 0; j < 4; j++) smT[(fq + j) * RSTR + row] = sv[s][j];
            }
        }
        __syncthreads();   // B3: smT ready

        // ---------- GEMM2: gates (r,z shared across both phases) ----------
        {
            float rr[3][4], zz[3][4], ni[3][4], nh[3][4];
#pragma unroll
            for (int s = 0; s < 3; s++)
#pragma unroll
                for (int j = 0; j < 4; j++) { rr[s][j] = 0.f; zz[s][j] = 0.f; ni[s][j] = 0.f; nh[s][j] = 0.f; }

            const float* smT = reg2;
            // phase 1: gi = sm @ Wc^T  (accumulate rr, zz, ni)
            {
                const float* Bb = Wg + fq;
#pragma unroll 2
                for (int k = 0; k < 128; k++) {
                    float a0v = smT[k * RSTR + r0];
                    float a1v = smT[k * RSTR + r1];
                    float a2v = smT[k * RSTR + r2];
                    const float* Bk = Bb + k * G3;
                    f32x4 br = *(const f32x4*)(Bk);
                    f32x4 bz = *(const f32x4*)(Bk + 128);
                    f32x4 bn = *(const f32x4*)(Bk + 256);
#pragma unroll
                    for (int j = 0; j < 4; j++) {
                        rr[0][j] = fmaf(a0v, br[j], rr[0][j]);
                        zz[0][j] = fmaf(a0v, bz[j], zz[0][j]);
                        ni[0][j] = fmaf(a0v, bn[j], ni[0][j]);
                        rr[1][j] = fmaf(a1v, br[j], rr[1][j]);
                        zz[1][j] = fmaf(a1v, bz[j], zz[1][j]);
                        ni[1][j] = fmaf(a1v, bn[j], ni[1][j]);
                        rr[2][j] = fmaf(a2v, br[j], rr[2][j]);
                        zz[2][j] = fmaf(a2v, bz[j], zz[2][j]);
                        ni[2][j] = fmaf(a2v, bn[j], ni[2][j]);
                    }
                }
            }
            // phase 2: gh = h @ W_hh^T  (accumulate rr, zz, nh)
            {
                const float* Bb = Wg + 128 * G3 + fq;
#pragma unroll 2
                for (int k = 0; k < 128; k++) {
                    float a0v = hT[k * RSTR + r0];
                    float a1v = hT[k * RSTR + r1];
                    float a2v = hT[k * RSTR + r2];
                    const float* Bk = Bb + k * G3;
                    f32x4 br = *(const f32x4*)(Bk);
                    f32x4 bz = *(const f32x4*)(Bk + 128);
                    f32x4 bn = *(const f32x4*)(Bk + 256);
#pragma unroll
                    for (int j = 0; j < 4; j++) {
                        rr[0][j] = fmaf(a0v, br[j], rr[0][j]);
                        zz[0][j] = fmaf(a0v, bz[j], zz[0][j]);
                        nh[0][j] = fmaf(a0v, bn[j], nh[0][j]);
                        rr[1][j] = fmaf(a1v, br[j], rr[1][j]);
                        zz[1][j] = fmaf(a1v, bz[j], zz[1][j]);
                        nh[1][j] = fmaf(a1v, bn[j], nh[1][j]);
                        rr[2][j] = fmaf(a2v, br[j], rr[2][j]);
                        zz[2][j] = fmaf(a2v, bz[j], zz[2][j]);
                        nh[2][j] = fmaf(a2v, bn[j], nh[2][j]);
                    }
                }
            }
            __syncthreads();   // B4: all smT/hT reads done

            // ---- GRU epilogue ----
            float b0v[4], e0v[4], b1v[4], e1v[4], b2v[4], e2v[4], b3v[4];
#pragma unroll
            for (int j = 0; j < 4; j++) {
                int m = fq + j;
                b0v[j] = baseL[m];        e0v[j] = extL[m];
                b1v[j] = baseL[128 + m];  e1v[j] = extL[128 + m];
                b2v[j] = baseL[256 + m];  e2v[j] = extL[256 + m];
                b3v[j] = baseL[384 + m];
            }
#pragma unroll
            for (int s = 0; s < 3; s++) {
                int row = rW + 32 * s;
                if (row >= NN) continue;
                float cf = (float)(goffL[row + 1] - goffL[row]);
#pragma unroll
                for (int j = 0; j < 4; j++) {
                    int m = fq + j;
                    float g0 = rr[s][j] + b0v[j] + cf * e0v[j];
                    float g1 = zz[s][j] + b1v[j] + cf * e1v[j];
                    float g2 = ni[s][j] + b2v[j] + cf * e2v[j];
                    float g3 = nh[s][j] + b3v[j];
                    float rg_ = 1.f / (1.f + __expf(-g0));
                    float z   = 1.f / (1.f + __expf(-g1));
                    float npre = g2 + rg_ * g3;
                    float ax = fabsf(npre);
                    float e  = __expf(-2.f * ax);
                    float tt = (1.f - e) / (1.f + e);
                    float n  = copysignf(tt, npre);
                    float ho = hT[m * RSTR + row];
                    float hn = (1.f - z) * n + z * ho;
                    hT[m * RSTR + row] = hn;
                }
            }
        }
        __syncthreads();   // B5: new h visible
    }

    // ======================= output head =======================
    // hid = relu(h @ W_o1^T + b_o1) -> reg2 (stride 132)
    {
        float acc[3][4];
#pragma unroll
        for (int s = 0; s < 3; s++)
#pragma unroll
            for (int j = 0; j < 4; j++) acc[s][j] = 0.f;
        const float* Bb = Wo1t + fq;
#pragma unroll 4
        for (int k = 0; k < 128; k++) {
            float a0v = hT[k * RSTR + r0];
            float a1v = hT[k * RSTR + r1];
            float a2v = hT[k * RSTR + r2];
            f32x4 b0 = *(const f32x4*)(Bb + k * 128);
#pragma unroll
            for (int j = 0; j < 4; j++) {
                acc[0][j] = fmaf(a0v, b0[j], acc[0][j]);
                acc[1][j] = fmaf(a1v, b0[j], acc[1][j]);
                acc[2][j] = fmaf(a2v, b0[j], acc[2][j]);
            }
        }
        float bo[4];
#pragma unroll
        for (int j = 0; j < 4; j++) bo[j] = b_o1[fq + j];
        __syncthreads();   // hT reads done; reg2 dead -> hid
#pragma unroll
        for (int s = 0; s < 3; s++) {
            int row = rW + 32 * s;
            if (row < NN) {
                float* dst = reg2 + row * HIDSTR + fq;
#pragma unroll
                for (int j = 0; j < 4; j++) dst[j] = fmaxf(acc[s][j] + bo[j], 0.f);
            }
        }
    }
    __syncthreads();
    // stage W_o2/b_o2 into hT area (hT dead)
    {
        float* wo2L = hT;
        float* bo2L = hT + 1152;
        for (int i = t; i < 9 * HH; i += 1024) wo2L[i] = W_o2[i];
        if (t < 9) bo2L[t] = b_o2[t];
    }
    __syncthreads();
    {
        const float* wo2L = hT;
        const float* bo2L = hT + 1152;
        for (int idx = t; idx < NN * 9; idx += 1024) {
            int r = idx / 9, qq = idx - 9 * r;
            float acc = bo2L[qq];
            const float* hrow = reg2 + r * HIDSTR;
            const float* wrow = wo2L + qq * HH;
            for (int k = 0; k < HH; k++) acc = fmaf(hrow[k], wrow[k], acc);
            out[((long)b * NN + r) * 9 + qq] = acc;
        }
    }
}

// ---------------------------------------------------------------------------
extern "C" void kernel_launch(void* const* d_in, const int* in_sizes, int n_in,
                              void* d_out, int out_size, void* d_ws, size_t ws_size,
                              hipStream_t stream) {
    const float* x      = (const float*)d_in[0];
    const int* ei       = (const int*)d_in[1];
    const float* W_in   = (const float*)d_in[2];
    const float* b_in   = (const float*)d_in[3];
    const float* W_m1   = (const float*)d_in[4];
    const float* b_m1   = (const float*)d_in[5];
    const float* W_m2   = (const float*)d_in[6];
    const float* b_m2   = (const float*)d_in[7];
    const float* W_ih   = (const float*)d_in[8];
    const float* W_hh   = (const float*)d_in[9];
    const float* b_ih   = (const float*)d_in[10];
    const float* b_hh   = (const float*)d_in[11];
    const float* W_o1   = (const float*)d_in[12];
    const float* b_o1   = (const float*)d_in[13];
    const float* W_o2   = (const float*)d_in[14];
    const float* b_o2   = (const float*)d_in[15];
    float* out = (float*)d_out;

    char* ws = (char*)d_ws;
    size_t off = 0;
    auto alloc = [&](size_t bytes) -> char* {
        char* p = ws + off;
        off += (bytes + 255) & ~(size_t)255;
        return p;
    };
    float* Wc    = (float*)alloc((size_t)G3 * HH * 4);
    float* W1t   = (float*)alloc(128 * 256 * 4);
    float* Wg    = (float*)alloc(2 * 128 * G3 * 4);
    float* Wo1t  = (float*)alloc(128 * 128 * 4);
    float* basev = (float*)alloc(512 * 4);
    float* extv  = (float*)alloc(512 * 4);
    int* goff    = (int*)alloc((NN + 1) * 4);
    int* gsend   = (int*)alloc(EE * 4);

    prep_graph<<<1, 128, 0, stream>>>(ei, goff, gsend);
    prep_wc<<<(G3 * HH + 255) / 256, 256, 0, stream>>>(W_ih, W_m2, Wc);
    prep_bias<<<2, 256, 0, stream>>>(W_ih, b_m2, b_ih, b_hh, basev, extv);
    prep_w1t<<<128, 256, 0, stream>>>(W_m1, W1t);
    prep_wg<<<384, 256, 0, stream>>>(Wc, W_hh, Wg);
    prep_wo1t<<<64, 256, 0, stream>>>(W_o1, Wo1t);

    (void)hipFuncSetAttribute((const void*)fused_rrn,
                              hipFuncAttributeMaxDynamicSharedMemorySize,
                              (int)LDS_BYTES);
    fused_rrn<<<BB, 1024, LDS_BYTES, stream>>>(
        x, W_in, b_in, b_m1, W1t, Wg, basev, extv,
        Wo1t, b_o1, W_o2, b_o2, goff, gsend, out);
}